// Round 9
// baseline (737.927 us; speedup 1.0000x reference)
//
#include <hip/hip_runtime.h>
#include <hip/hip_fp16.h>

#define N_NODES 50000
#define N_EDGES 800000
#define IN_DIM  128
#define EDGE_DIM 16
#define HID     64
#define HID2    128
#define OUT_DIM 8
#define N_LAYERS 4
#define NBUCK   391        // ceil(50000/128) buckets of 128 dst nodes
#define CCHUNK  4096       // edges per coarse block
#define CBLOCKS 196        // ceil(800000/4096)

typedef _Float16 half8 __attribute__((ext_vector_type(8)));
typedef float floatx4 __attribute__((ext_vector_type(4)));

// wave-uniform broadcast of lane l's float via v_readlane (SGPR result,
// folds into v_fma as the 1 allowed scalar operand; avoids ds_bpermute)
static __device__ __forceinline__ float bcast(float v, int l) {
    return __uint_as_float(__builtin_amdgcn_readlane(__float_as_uint(v), l));
}

// ---------------------------------------------------------------------------
// Two-level counting sort by dst.
// Entry packing: word0 = src | dst<<16 (both < 2^16), word1 = edge id.
// ---------------------------------------------------------------------------
__global__ __launch_bounds__(256, 4) void chist_kernel(
    const int* __restrict__ dsts, int* __restrict__ ccnt)
{
    __shared__ int lh[NBUCK];
    for (int i = threadIdx.x; i < NBUCK; i += 256) lh[i] = 0;
    __syncthreads();
    const int base = blockIdx.x * CCHUNK;
#pragma unroll
    for (int i = 0; i < 16; ++i) {
        const int e = base + i * 256 + threadIdx.x;
        if (e < N_EDGES) atomicAdd(&lh[dsts[e] >> 7], 1);
    }
    __syncthreads();
    for (int i = threadIdx.x; i < NBUCK; i += 256)
        if (lh[i]) atomicAdd(&ccnt[i], lh[i]);
}

// single block: exclusive scan of 391 bucket counts -> coff[0..391], ccur copy
__global__ __launch_bounds__(256, 1) void cscan_kernel(
    const int* __restrict__ ccnt, int* __restrict__ coff, int* __restrict__ ccur)
{
    __shared__ int part[512];
    const int t = threadIdx.x;
    part[t]       = (t < NBUCK)       ? ccnt[t]       : 0;
    part[t + 256] = (t + 256 < NBUCK) ? ccnt[t + 256] : 0;
    __syncthreads();
    for (int off = 1; off < 512; off <<= 1) {
        const int v0 = (t >= off) ? part[t - off] : 0;
        const int v1 = (t + 256 >= off) ? part[t + 256 - off] : 0;
        __syncthreads();
        part[t] += v0; part[t + 256] += v1;
        __syncthreads();
    }
    if (t < NBUCK) { const int ex = (t > 0) ? part[t - 1] : 0; coff[t] = ex; ccur[t] = ex; }
    const int i2 = t + 256;
    if (i2 < NBUCK) { coff[i2] = part[i2 - 1]; ccur[i2] = part[i2 - 1]; }
    if (t == 0) coff[NBUCK] = part[NBUCK - 1];
}

__global__ __launch_bounds__(256, 4) void cscatter_kernel(
    const int* __restrict__ srcs, const int* __restrict__ dsts,
    int* __restrict__ ccur, uint2* __restrict__ tmp)
{
    __shared__ int lh[NBUCK], lbase[NBUCK], lrank[NBUCK];
    for (int i = threadIdx.x; i < NBUCK; i += 256) { lh[i] = 0; lrank[i] = 0; }
    __syncthreads();
    const int base = blockIdx.x * CCHUNK;
    int myd[16], mys[16];
#pragma unroll
    for (int i = 0; i < 16; ++i) {
        const int e = base + i * 256 + threadIdx.x;
        if (e < N_EDGES) {
            myd[i] = dsts[e]; mys[i] = srcs[e];
            atomicAdd(&lh[myd[i] >> 7], 1);
        } else myd[i] = -1;
    }
    __syncthreads();
    for (int i = threadIdx.x; i < NBUCK; i += 256) {
        const int c = lh[i];
        lbase[i] = c ? atomicAdd(&ccur[i], c) : 0;
    }
    __syncthreads();
#pragma unroll
    for (int i = 0; i < 16; ++i) {
        if (myd[i] >= 0) {
            const int e = base + i * 256 + threadIdx.x;
            const int b = myd[i] >> 7;
            const int r = atomicAdd(&lrank[b], 1);
            tmp[lbase[b] + r] =
                make_uint2((unsigned)mys[i] | ((unsigned)myd[i] << 16),
                           (unsigned)e);
        }
    }
}

// one block per bucket: LDS counting sort over the 128 local dsts
__global__ __launch_bounds__(256, 1) void fsort_kernel(
    const uint2* __restrict__ tmp, const int* __restrict__ coff,
    unsigned* __restrict__ sd2, int* __restrict__ eid)
{
    __shared__ uint2 ebuf[4096];
    __shared__ int lh[128], lsc[128];
    const int b = blockIdx.x;
    const int lo = coff[b];
    const int cnt = coff[b + 1] - lo;
    if (threadIdx.x < 128) lh[threadIdx.x] = 0;
    __syncthreads();
    for (int i = threadIdx.x; i < cnt; i += 256) {
        const uint2 v = tmp[lo + i];
        ebuf[i] = v;
        atomicAdd(&lh[(int)(v.x >> 16) - b * 128], 1);
    }
    __syncthreads();
    if (threadIdx.x < 128) lsc[threadIdx.x] = lh[threadIdx.x];
    __syncthreads();
    for (int off = 1; off < 128; off <<= 1) {
        int v = 0;
        if (threadIdx.x < 128 && threadIdx.x >= off) v = lsc[threadIdx.x - off];
        __syncthreads();
        if (threadIdx.x < 128) lsc[threadIdx.x] += v;
        __syncthreads();
    }
    if (threadIdx.x < 128) lh[threadIdx.x] = lsc[threadIdx.x] - lh[threadIdx.x];
    __syncthreads();
    for (int i = threadIdx.x; i < cnt; i += 256) {
        const uint2 v = ebuf[i];
        const int d = (int)(v.x >> 16) - b * 128;
        const int pos = atomicAdd(&lh[d], 1);
        sd2[lo + pos] = v.x;
        eid[lo + pos] = (int)v.y;
    }
}

// ---------------------------------------------------------------------------
// h0 = x @ node_W + node_b   [N,128]@[128,64]
// 4 nodes per WAVE, barrier-free; W register-resident (128 VGPR); x inputs
// (2 floats/node) loaded up-front; readlane-broadcast FMAs, 4 indep chains.
// ---------------------------------------------------------------------------
__global__ __launch_bounds__(256, 3) void node_proj_kernel(
    const float* __restrict__ x, const float* __restrict__ W,
    const float* __restrict__ b, float* __restrict__ h, __half* __restrict__ zh)
{
    const int lane = threadIdx.x & 63;
    const int wave = (blockIdx.x * 256 + threadIdx.x) >> 6;   // 0..12499

    float w[IN_DIM];
#pragma unroll
    for (int k = 0; k < IN_DIM; ++k) w[k] = W[k * HID + lane];
    const float bias = b[lane];

    float xa[4], xb[4];
#pragma unroll
    for (int i = 0; i < 4; ++i) {
        const size_t xbase = (size_t)(wave + i * 12500) * IN_DIM;
        xa[i] = x[xbase + lane];
        xb[i] = x[xbase + 64 + lane];
    }

#pragma unroll
    for (int pr = 0; pr < 2; ++pr) {                 // node pairs (0,1),(2,3)
        const int i0 = pr * 2, i1 = pr * 2 + 1;
        float a0 = 0.f, a1 = 0.f, d0 = 0.f, d1 = 0.f;
#pragma unroll
        for (int k = 0; k < 64; ++k) {
            a0 = fmaf(bcast(xa[i0], k), w[k],      a0);
            a1 = fmaf(bcast(xb[i0], k), w[k + 64], a1);
            d0 = fmaf(bcast(xa[i1], k), w[k],      d0);
            d1 = fmaf(bcast(xb[i1], k), w[k + 64], d1);
        }
        const float u0 = (a0 + a1) + bias;
        const float u1 = (d0 + d1) + bias;
        const int n0 = wave + i0 * 12500, n1 = wave + i1 * 12500;
        h[n0 * HID + lane] = u0;
        zh[n0 * HID + lane] = __float2half(u0);
        h[n1 * HID + lane] = u1;
        zh[n1 * HID + lane] = __float2half(u1);
    }
}

// ---------------------------------------------------------------------------
// edge embedding via MFMA (16 edges/wave, K padded 16->32), LDS transpose.
// Grid 3125: 4 tiles per wave -- the grid-stride loop IS the pipeline
// (tile k+1 gathers overlap tile k MFMA/store). One-tile-per-wave measured
// 84us vs 52us here (round 7).
// ---------------------------------------------------------------------------
__global__ __launch_bounds__(256, 4) void edge_emb_kernel(
    const float* __restrict__ ea, const float* __restrict__ W,
    const float* __restrict__ b, const int* __restrict__ eid,
    __half* __restrict__ eah)
{
    __shared__ __half lds_t[4][16 * HID];            // 2KB per wave
    const int lane = threadIdx.x & 63;
    const int waveid = threadIdx.x >> 6;
    const int wave = (blockIdx.x * 256 + threadIdx.x) >> 6;
    const int nwaves = gridDim.x * 4;
    const int m = lane & 15, q = lane >> 4;
    const int NT = N_EDGES / 16;                     // 50000

    half8 bf[4];
#pragma unroll
    for (int blk = 0; blk < 4; ++blk) {
#pragma unroll
        for (int i = 0; i < 8; ++i) {
            const int k = q * 8 + i;
            bf[blk][i] = (k < EDGE_DIM)
                ? (_Float16)W[k * HID + blk * 16 + m] : (_Float16)0.f;
        }
    }
    float bv[4];
#pragma unroll
    for (int blk = 0; blk < 4; ++blk) bv[blk] = b[blk * 16 + m];

    const int ed = lane >> 3, ch = lane & 7;         // store mapping

    for (int tile = wave; tile < NT; tile += nwaves) {
        const int e0 = tile * 16;
        const int eidx = eid[e0 + m];                // gather source row id
        half8 af;
#pragma unroll
        for (int i = 0; i < 8; ++i) af[i] = (_Float16)0.f;
        if (q < 2) {
            const float4* ap =
                (const float4*)(ea + (size_t)eidx * EDGE_DIM + q * 8);
            const float4 lo = ap[0];
            const float4 hi = ap[1];
            af[0] = (_Float16)lo.x; af[1] = (_Float16)lo.y;
            af[2] = (_Float16)lo.z; af[3] = (_Float16)lo.w;
            af[4] = (_Float16)hi.x; af[5] = (_Float16)hi.y;
            af[6] = (_Float16)hi.z; af[7] = (_Float16)hi.w;
        }
        floatx4 c[4];
#pragma unroll
        for (int blk = 0; blk < 4; ++blk) {
            floatx4 cin = {bv[blk], bv[blk], bv[blk], bv[blk]};
            c[blk] = __builtin_amdgcn_mfma_f32_16x16x32_f16(
                af, bf[blk], cin, 0, 0, 0);
        }
#pragma unroll
        for (int blk = 0; blk < 4; ++blk)
#pragma unroll
            for (int r = 0; r < 4; ++r)
                lds_t[waveid][(q * 4 + r) * HID + blk * 16 + m] =
                    __float2half(c[blk][r]);
        // streaming contiguous stores: 2x 16B per lane
        const float4 v0 =
            *(const float4*)&lds_t[waveid][ed * HID + ch * 8];
        const float4 v1 =
            *(const float4*)&lds_t[waveid][(8 + ed) * HID + ch * 8];
        ((float4*)(eah + (size_t)(e0 + ed) * HID))[ch] = v0;
        ((float4*)(eah + (size_t)(e0 + 8 + ed) * HID))[ch] = v1;
    }
}

// ---------------------------------------------------------------------------
// Edge-major segmented softmax-aggregate, interior plain stores,
// CROSS-TILE PIPELINED: grid 782 -> ~4 tiles/wave; next tile's sdv + 64 ez
// streaming loads are issued before the current tile's compute (explicit
// double-buffer), hiding the ez stream latency under za gathers + VALU.
// ---------------------------------------------------------------------------
__global__ __launch_bounds__(256, 3) void edge_agg_kernel(
    const __half* __restrict__ zh, const __half* __restrict__ eah,
    const unsigned* __restrict__ sd2,
    const float* __restrict__ conv_t, int layer,
    float2* __restrict__ ps)
{
    const int lane = threadIdx.x & 63;
    const int nwaves = gridDim.x * 4;
    const float t2 = conv_t[layer] * 1.4426950408889634f;  // log2(e)*t
    const int NT = N_EDGES / 64;                     // 12500

    const _Float16* zf = (const _Float16*)zh;
    const _Float16* ef = (const _Float16*)eah;

    int tile = (blockIdx.x * 256 + threadIdx.x) >> 6;
    if (tile >= NT) return;

    // prologue: current tile's sdv + ez
    unsigned sdv = sd2[tile * 64 + lane];
    _Float16 ez[64];
    {
        const _Float16* erow = ef + (size_t)tile * 64 * HID + lane;
#pragma unroll
        for (int k = 0; k < 64; ++k) ez[k] = erow[(size_t)k * HID];
    }

    while (true) {
        const int nxt = tile + nwaves;
        unsigned sdv_n = 0;
        _Float16 ezn[64];
        if (nxt < NT) {                              // prefetch next tile
            sdv_n = sd2[nxt * 64 + lane];
            const _Float16* erown = ef + (size_t)nxt * 64 * HID + lane;
#pragma unroll
            for (int k = 0; k < 64; ++k) ezn[k] = erown[(size_t)k * HID];
        }

        // ---- process current tile ----
        const int sv = (int)(sdv & 0xffffu);
        const int dv = (int)(sdv >> 16);
        const int pv = __shfl_up(dv, 1, 64);
        const unsigned long long bmask = __ballot(dv != pv) & ~1ull;

        _Float16 za[16], zb[16];
#pragma unroll
        for (int k = 0; k < 16; ++k) {               // prologue: group 0
            const int a = __builtin_amdgcn_readlane(sv, k);
            za[k] = zf[(size_t)a * HID + lane];
        }

        float S = 0.f, P = 0.f;
        int cur = __builtin_amdgcn_readlane(dv, 0);
        bool first = true;
#pragma unroll
        for (int g = 0; g < 4; ++g) {
            if (g < 3) {                             // prefetch group g+1
#pragma unroll
                for (int k = 0; k < 16; ++k) {
                    const int a = __builtin_amdgcn_readlane(sv, (g + 1) * 16 + k);
                    zb[k] = zf[(size_t)a * HID + lane];
                }
            }
#pragma unroll
            for (int k = 0; k < 16; ++k) {
                const int j = g * 16 + k;
                if (bmask & (1ull << j)) {           // SALU test, uniform
                    float2* addr = &ps[(size_t)cur * HID + lane];
                    if (first) {                     // may span from prev tile
                        unsafeAtomicAdd(&addr->x, P);
                        unsafeAtomicAdd(&addr->y, S);
                        first = false;
                    } else {                         // complete node: store
                        *addr = make_float2(P, S);
                    }
                    S = 0.f; P = 0.f;
                    cur = __builtin_amdgcn_readlane(dv, j);
                }
                _Float16 mh = za[k] + ez[j];
                mh = mh > (_Float16)0.f ? mh : (_Float16)0.f;
                const float mm = (float)mh + 1e-7f;
                const float xx = __builtin_amdgcn_exp2f(mm * t2);
                S += xx;
                P = fmaf(mm, xx, P);
            }
            if (g < 3) {
#pragma unroll
                for (int k = 0; k < 16; ++k) za[k] = zb[k];
            }
        }
        {   // final flush: may span into next tile -> atomic
            float2* addr = &ps[(size_t)cur * HID + lane];
            unsafeAtomicAdd(&addr->x, P);
            unsafeAtomicAdd(&addr->y, S);
        }

        if (nxt >= NT) break;
        tile = nxt;
        sdv = sdv_n;
#pragma unroll
        for (int k = 0; k < 64; ++k) ez[k] = ezn[k]; // buffer swap (reg movs)
    }
}

// ---------------------------------------------------------------------------
// mm1: 4 nodes per WAVE (wave, +12500, +25000, +37500), barrier-free.
// ALL node inputs loaded up-front (loads strictly before the ps re-zero
// stores), then two node-pairs computed back-to-back with 8 independent
// FMA chains and interleaved LN butterflies.
// ---------------------------------------------------------------------------
__global__ __launch_bounds__(256, 3) void node_mm1_kernel(
    float2* __restrict__ ps,
    const __half* __restrict__ zh,
    const float* __restrict__ W1, const float* __restrict__ b1,
    const float* __restrict__ g1, const float* __restrict__ be1,
    __half* __restrict__ vh)
{
    const int lane = threadIdx.x & 63;
    const int wave = (blockIdx.x * 256 + threadIdx.x) >> 6;   // 0..12499

    float wa[HID], wb[HID];
#pragma unroll
    for (int k = 0; k < HID; ++k) {
        wa[k] = W1[k * HID2 + lane];
        wb[k] = W1[k * HID2 + 64 + lane];
    }
    const float ba = b1[lane],  bb = b1[64 + lane];
    const float ga = g1[lane],  gb = g1[64 + lane];
    const float ca = be1[lane], cb = be1[64 + lane];

    int idx[4];
    float2 pv[4];
    float zv[4];
#pragma unroll
    for (int i = 0; i < 4; ++i) idx[i] = (wave + i * 12500) * HID + lane;
#pragma unroll
    for (int i = 0; i < 4; ++i) pv[i] = ps[idx[i]];          // all loads first
#pragma unroll
    for (int i = 0; i < 4; ++i) zv[i] = __half2float(zh[idx[i]]);
#pragma unroll
    for (int i = 0; i < 4; ++i) ps[idx[i]] = make_float2(0.f, 0.f); // re-zero
    float hv[4];
#pragma unroll
    for (int i = 0; i < 4; ++i)
        hv[i] = pv[i].x / (pv[i].y + 1e-16f) + zv[i];

#pragma unroll
    for (int pr = 0; pr < 2; ++pr) {                 // node pairs (0,1),(2,3)
        const float h0 = hv[pr * 2], h1 = hv[pr * 2 + 1];
        float a0 = 0.f, a1 = 0.f, c0 = 0.f, c1 = 0.f;   // node pr*2
        float d0 = 0.f, d1 = 0.f, e0 = 0.f, e1 = 0.f;   // node pr*2+1
#pragma unroll
        for (int k = 0; k < 32; ++k) {
            const float x0 = bcast(h0, k);
            const float x1 = bcast(h0, k + 32);
            const float y0 = bcast(h1, k);
            const float y1 = bcast(h1, k + 32);
            a0 = fmaf(x0, wa[k], a0);
            c0 = fmaf(x0, wb[k], c0);
            a1 = fmaf(x1, wa[k + 32], a1);
            c1 = fmaf(x1, wb[k + 32], c1);
            d0 = fmaf(y0, wa[k], d0);
            e0 = fmaf(y0, wb[k], e0);
            d1 = fmaf(y1, wa[k + 32], d1);
            e1 = fmaf(y1, wb[k + 32], e1);
        }
        const float ua0 = (a0 + a1) + ba, ub0 = (c0 + c1) + bb;
        const float ua1 = (d0 + d1) + ba, ub1 = (e0 + e1) + bb;

        float s0 = ua0 + ub0, s1 = ua1 + ub1;        // LN128, interleaved
#pragma unroll
        for (int o = 1; o < 64; o <<= 1) {
            s0 += __shfl_xor(s0, o, 64);
            s1 += __shfl_xor(s1, o, 64);
        }
        const float mu0 = s0 * (1.f / 128.f), mu1 = s1 * (1.f / 128.f);
        const float da0 = ua0 - mu0, db0 = ub0 - mu0;
        const float da1 = ua1 - mu1, db1 = ub1 - mu1;
        float q0 = fmaf(da0, da0, db0 * db0);
        float q1 = fmaf(da1, da1, db1 * db1);
#pragma unroll
        for (int o = 1; o < 64; o <<= 1) {
            q0 += __shfl_xor(q0, o, 64);
            q1 += __shfl_xor(q1, o, 64);
        }
        const float r0 = rsqrtf(q0 * (1.f / 128.f) + 1e-5f);
        const float r1 = rsqrtf(q1 * (1.f / 128.f) + 1e-5f);
        const float ya0 = da0 * r0 * ga + ca, yb0 = db0 * r0 * gb + cb;
        const float ya1 = da1 * r1 * ga + ca, yb1 = db1 * r1 * gb + cb;
        const size_t v0 = (size_t)(wave + pr * 2 * 12500) * HID2;
        const size_t v1 = (size_t)(wave + (pr * 2 + 1) * 12500) * HID2;
        vh[v0 + lane]      = __float2half(ya0 > 0.f ? ya0 : 0.f);
        vh[v0 + 64 + lane] = __float2half(yb0 > 0.f ? yb0 : 0.f);
        vh[v1 + lane]      = __float2half(ya1 > 0.f ? ya1 : 0.f);
        vh[v1 + 64 + lane] = __float2half(yb1 > 0.f ? yb1 : 0.f);
    }
}

// ---------------------------------------------------------------------------
// mm2: 4 nodes per WAVE (same decomposition as mm1), barrier-free.
// All vh/h inputs loaded up-front; node pairs with 8 indep chains;
// interleaved LN64 butterflies.
// ---------------------------------------------------------------------------
__global__ __launch_bounds__(256, 3) void node_mm2_kernel(
    const __half* __restrict__ vh,
    const float* __restrict__ W2, const float* __restrict__ b2,
    const float* __restrict__ lng, const float* __restrict__ lnb,
    float* __restrict__ h, __half* __restrict__ zh, int residual)
{
    const int lane = threadIdx.x & 63;
    const int wave = (blockIdx.x * 256 + threadIdx.x) >> 6;   // 0..12499

    float wa[HID], wb[HID];     // wa[k]=W2[k][c], wb[k]=W2[k+64][c]
#pragma unroll
    for (int k = 0; k < HID; ++k) {
        wa[k] = W2[k * HID + lane];
        wb[k] = W2[(k + 64) * HID + lane];
    }
    const float bias = b2[lane];
    const float g = lng[lane];
    const float be = lnb[lane];

    int idx[4];
    float f0[4], f1[4], hold[4];
#pragma unroll
    for (int i = 0; i < 4; ++i) idx[i] = (wave + i * 12500) * HID + lane;
#pragma unroll
    for (int i = 0; i < 4; ++i) {
        const size_t vb = (size_t)(wave + i * 12500) * HID2;
        f0[i] = __half2float(vh[vb + lane]);
        f1[i] = __half2float(vh[vb + 64 + lane]);
    }
#pragma unroll
    for (int i = 0; i < 4; ++i) hold[i] = h[idx[i]];

#pragma unroll
    for (int pr = 0; pr < 2; ++pr) {                 // node pairs (0,1),(2,3)
        const int i0 = pr * 2, i1 = pr * 2 + 1;
        float a0 = 0.f, a1 = 0.f, c0 = 0.f, c1 = 0.f;   // node i0
        float d0 = 0.f, d1 = 0.f, e0 = 0.f, e1 = 0.f;   // node i1
#pragma unroll
        for (int k = 0; k < 32; ++k) {
            a0 = fmaf(bcast(f0[i0], k),      wa[k],      a0);
            a1 = fmaf(bcast(f0[i0], k + 32), wa[k + 32], a1);
            c0 = fmaf(bcast(f1[i0], k),      wb[k],      c0);
            c1 = fmaf(bcast(f1[i0], k + 32), wb[k + 32], c1);
            d0 = fmaf(bcast(f0[i1], k),      wa[k],      d0);
            d1 = fmaf(bcast(f0[i1], k + 32), wa[k + 32], d1);
            e0 = fmaf(bcast(f1[i1], k),      wb[k],      e0);
            e1 = fmaf(bcast(f1[i1], k + 32), wb[k + 32], e1);
        }
        const float acc0 = (a0 + a1) + (c0 + c1) + bias;
        const float acc1 = (d0 + d1) + (e0 + e1) + bias;
        const float hn0 = residual ? (hold[i0] + acc0) : acc0;
        const float hn1 = residual ? (hold[i1] + acc1) : acc1;
        h[idx[i0]] = hn0;
        h[idx[i1]] = hn1;

        float s0 = hn0, s1 = hn1;                    // LN64, interleaved
#pragma unroll
        for (int o = 1; o < 64; o <<= 1) {
            s0 += __shfl_xor(s0, o, 64);
            s1 += __shfl_xor(s1, o, 64);
        }
        const float mu0 = s0 * (1.f / 64.f), mu1 = s1 * (1.f / 64.f);
        const float dd0 = hn0 - mu0, dd1 = hn1 - mu1;
        float q0 = dd0 * dd0, q1 = dd1 * dd1;
#pragma unroll
        for (int o = 1; o < 64; o <<= 1) {
            q0 += __shfl_xor(q0, o, 64);
            q1 += __shfl_xor(q1, o, 64);
        }
        const float r0 = rsqrtf(q0 * (1.f / 64.f) + 1e-5f);
        const float r1 = rsqrtf(q1 * (1.f / 64.f) + 1e-5f);
        const float y0 = dd0 * r0 * g + be;
        const float y1 = dd1 * r1 * g + be;
        zh[idx[i0]] = __float2half(y0 > 0.f ? y0 : 0.f);
        zh[idx[i1]] = __float2half(y1 > 0.f ? y1 : 0.f);
    }
}

// ---------------------------------------------------------------------------
// out = zh @ lin_W + lin_b      [N,64]@[64,8]
// ---------------------------------------------------------------------------
__global__ __launch_bounds__(256, 4) void final_kernel(
    const __half* __restrict__ zh, const float* __restrict__ Wl,
    const float* __restrict__ bl, float* __restrict__ out)
{
    __shared__ float wl[HID * OUT_DIM];
    for (int i = threadIdx.x; i < HID * OUT_DIM; i += 256) wl[i] = Wl[i];
    __syncthreads();
    const int total = N_NODES * OUT_DIM;
    for (int idx = blockIdx.x * 256 + threadIdx.x; idx < total;
         idx += gridDim.x * 256) {
        const int n = idx >> 3, o = idx & 7;
        const __half2* zp = (const __half2*)(zh + (size_t)n * HID);
        float acc = bl[o];
#pragma unroll
        for (int k2 = 0; k2 < HID / 2; ++k2) {
            const float2 f = __half22float2(zp[k2]);
            acc = fmaf(f.x, wl[(k2 * 2 + 0) * OUT_DIM + o], acc);
            acc = fmaf(f.y, wl[(k2 * 2 + 1) * OUT_DIM + o], acc);
        }
        out[idx] = acc;
    }
}

// ---------------------------------------------------------------------------
extern "C" void kernel_launch(void* const* d_in, const int* in_sizes, int n_in,
                              void* d_out, int out_size, void* d_ws, size_t ws_size,
                              hipStream_t stream)
{
    const float* x         = (const float*)d_in[0];
    const float* edge_attr = (const float*)d_in[1];
    const float* node_W    = (const float*)d_in[2];
    const float* node_b    = (const float*)d_in[3];
    const float* edge_W    = (const float*)d_in[4];
    const float* edge_b    = (const float*)d_in[5];
    const float* conv_t    = (const float*)d_in[6];
    const float* conv_W1   = (const float*)d_in[7];
    const float* conv_b1   = (const float*)d_in[8];
    const float* conv_g1   = (const float*)d_in[9];
    const float* conv_be1  = (const float*)d_in[10];
    const float* conv_W2   = (const float*)d_in[11];
    const float* conv_b2   = (const float*)d_in[12];
    const float* ln_g      = (const float*)d_in[13];
    const float* ln_b      = (const float*)d_in[14];
    const float* lin_W     = (const float*)d_in[15];
    const float* lin_b     = (const float*)d_in[16];
    const int*   edge_index= (const int*)d_in[17];
    const int*   srcs = edge_index;
    const int*   dsts = edge_index + N_EDGES;
    float* out = (float*)d_out;

    // workspace layout (~173 MB)
    float* h    = (float*)d_ws;                   // N*64
    float2* ps  = (float2*)(h + N_NODES * HID);   // N*64 float2 (P,S packed)
    __half* vh  = (__half*)(ps + N_NODES * HID);  // N*128 half
    __half* zh  = vh + (size_t)N_NODES * HID2;    // N*64 half
    __half* eah = zh + (size_t)N_NODES * HID;     // E*64 half
    uint2* tmp  = (uint2*)(eah + (size_t)N_EDGES * HID); // E x 8B
    unsigned* sd2 = (unsigned*)(tmp + N_EDGES);   // E x 4B
    int* eid    = (int*)(sd2 + N_EDGES);          // E x 4B
    int* ccnt   = eid + N_EDGES;                  // NBUCK
    int* coff   = ccnt + NBUCK;                   // NBUCK+1
    int* ccur   = coff + NBUCK + 1;               // NBUCK

    // ---- two-level counting sort of edges by dst ----
    hipMemsetAsync(ccnt, 0, (size_t)NBUCK * sizeof(int), stream);
    chist_kernel<<<CBLOCKS, 256, 0, stream>>>(dsts, ccnt);
    cscan_kernel<<<1, 256, 0, stream>>>(ccnt, coff, ccur);
    cscatter_kernel<<<CBLOCKS, 256, 0, stream>>>(srcs, dsts, ccur, tmp);
    fsort_kernel<<<NBUCK, 256, 0, stream>>>(tmp, coff, sd2, eid);

    node_proj_kernel<<<3125, 256, 0, stream>>>(x, node_W, node_b, h, zh);
    edge_emb_kernel<<<3125, 256, 0, stream>>>(edge_attr, edge_W, edge_b, eid, eah);

    // zero ps once; node_mm1 re-zeroes it for the next layer
    hipMemsetAsync(ps, 0, (size_t)N_NODES * HID * sizeof(float2), stream);

    for (int layer = 0; layer < N_LAYERS; ++layer) {
        edge_agg_kernel<<<782, 256, 0, stream>>>(zh, eah, sd2,
                                                 conv_t, layer, ps);
        node_mm1_kernel<<<3125, 256, 0, stream>>>(
            ps, zh,
            conv_W1 + (size_t)layer * HID * HID2, conv_b1 + layer * HID2,
            conv_g1 + layer * HID2, conv_be1 + layer * HID2, vh);
        const float* gz = (layer < N_LAYERS - 1) ? (ln_g + (layer + 1) * HID) : ln_g;
        const float* bz = (layer < N_LAYERS - 1) ? (ln_b + (layer + 1) * HID) : ln_b;
        node_mm2_kernel<<<3125, 256, 0, stream>>>(
            vh, conv_W2 + (size_t)layer * HID2 * HID, conv_b2 + layer * HID,
            gz, bz, h, zh, layer > 0 ? 1 : 0);
    }
    final_kernel<<<1024, 256, 0, stream>>>(zh, lin_W, lin_b, out);
}

// Round 10
// 644.915 us; speedup vs baseline: 1.1442x; 1.1442x over previous
//
#include <hip/hip_runtime.h>
#include <hip/hip_fp16.h>

#define N_NODES 50000
#define N_EDGES 800000
#define IN_DIM  128
#define EDGE_DIM 16
#define HID     64
#define HID2    128
#define OUT_DIM 8
#define N_LAYERS 4
#define NBUCK   391        // ceil(50000/128) buckets of 128 dst nodes
#define CCHUNK  4096       // edges per coarse block
#define CBLOCKS 196        // ceil(800000/4096)

typedef _Float16 half8 __attribute__((ext_vector_type(8)));
typedef float floatx4 __attribute__((ext_vector_type(4)));

// wave-uniform broadcast of lane l's float via v_readlane (SGPR result,
// folds into v_fma as the 1 allowed scalar operand; avoids ds_bpermute)
static __device__ __forceinline__ float bcast(float v, int l) {
    return __uint_as_float(__builtin_amdgcn_readlane(__float_as_uint(v), l));
}

// ---------------------------------------------------------------------------
// Two-level counting sort by dst.
// Entry packing: word0 = src | dst<<16 (both < 2^16), word1 = edge id.
// ---------------------------------------------------------------------------
__global__ __launch_bounds__(256, 4) void chist_kernel(
    const int* __restrict__ dsts, int* __restrict__ ccnt)
{
    __shared__ int lh[NBUCK];
    for (int i = threadIdx.x; i < NBUCK; i += 256) lh[i] = 0;
    __syncthreads();
    const int base = blockIdx.x * CCHUNK;
#pragma unroll
    for (int i = 0; i < 16; ++i) {
        const int e = base + i * 256 + threadIdx.x;
        if (e < N_EDGES) atomicAdd(&lh[dsts[e] >> 7], 1);
    }
    __syncthreads();
    for (int i = threadIdx.x; i < NBUCK; i += 256)
        if (lh[i]) atomicAdd(&ccnt[i], lh[i]);
}

// single block: exclusive scan of 391 bucket counts -> coff[0..391], ccur copy
__global__ __launch_bounds__(256, 1) void cscan_kernel(
    const int* __restrict__ ccnt, int* __restrict__ coff, int* __restrict__ ccur)
{
    __shared__ int part[512];
    const int t = threadIdx.x;
    part[t]       = (t < NBUCK)       ? ccnt[t]       : 0;
    part[t + 256] = (t + 256 < NBUCK) ? ccnt[t + 256] : 0;
    __syncthreads();
    for (int off = 1; off < 512; off <<= 1) {
        const int v0 = (t >= off) ? part[t - off] : 0;
        const int v1 = (t + 256 >= off) ? part[t + 256 - off] : 0;
        __syncthreads();
        part[t] += v0; part[t + 256] += v1;
        __syncthreads();
    }
    if (t < NBUCK) { const int ex = (t > 0) ? part[t - 1] : 0; coff[t] = ex; ccur[t] = ex; }
    const int i2 = t + 256;
    if (i2 < NBUCK) { coff[i2] = part[i2 - 1]; ccur[i2] = part[i2 - 1]; }
    if (t == 0) coff[NBUCK] = part[NBUCK - 1];
}

__global__ __launch_bounds__(256, 4) void cscatter_kernel(
    const int* __restrict__ srcs, const int* __restrict__ dsts,
    int* __restrict__ ccur, uint2* __restrict__ tmp)
{
    __shared__ int lh[NBUCK], lbase[NBUCK], lrank[NBUCK];
    for (int i = threadIdx.x; i < NBUCK; i += 256) { lh[i] = 0; lrank[i] = 0; }
    __syncthreads();
    const int base = blockIdx.x * CCHUNK;
    int myd[16], mys[16];
#pragma unroll
    for (int i = 0; i < 16; ++i) {
        const int e = base + i * 256 + threadIdx.x;
        if (e < N_EDGES) {
            myd[i] = dsts[e]; mys[i] = srcs[e];
            atomicAdd(&lh[myd[i] >> 7], 1);
        } else myd[i] = -1;
    }
    __syncthreads();
    for (int i = threadIdx.x; i < NBUCK; i += 256) {
        const int c = lh[i];
        lbase[i] = c ? atomicAdd(&ccur[i], c) : 0;
    }
    __syncthreads();
#pragma unroll
    for (int i = 0; i < 16; ++i) {
        if (myd[i] >= 0) {
            const int e = base + i * 256 + threadIdx.x;
            const int b = myd[i] >> 7;
            const int r = atomicAdd(&lrank[b], 1);
            tmp[lbase[b] + r] =
                make_uint2((unsigned)mys[i] | ((unsigned)myd[i] << 16),
                           (unsigned)e);
        }
    }
}

// one block per bucket: LDS counting sort over the 128 local dsts
__global__ __launch_bounds__(256, 1) void fsort_kernel(
    const uint2* __restrict__ tmp, const int* __restrict__ coff,
    unsigned* __restrict__ sd2, int* __restrict__ eid)
{
    __shared__ uint2 ebuf[4096];
    __shared__ int lh[128], lsc[128];
    const int b = blockIdx.x;
    const int lo = coff[b];
    const int cnt = coff[b + 1] - lo;
    if (threadIdx.x < 128) lh[threadIdx.x] = 0;
    __syncthreads();
    for (int i = threadIdx.x; i < cnt; i += 256) {
        const uint2 v = tmp[lo + i];
        ebuf[i] = v;
        atomicAdd(&lh[(int)(v.x >> 16) - b * 128], 1);
    }
    __syncthreads();
    if (threadIdx.x < 128) lsc[threadIdx.x] = lh[threadIdx.x];
    __syncthreads();
    for (int off = 1; off < 128; off <<= 1) {
        int v = 0;
        if (threadIdx.x < 128 && threadIdx.x >= off) v = lsc[threadIdx.x - off];
        __syncthreads();
        if (threadIdx.x < 128) lsc[threadIdx.x] += v;
        __syncthreads();
    }
    if (threadIdx.x < 128) lh[threadIdx.x] = lsc[threadIdx.x] - lh[threadIdx.x];
    __syncthreads();
    for (int i = threadIdx.x; i < cnt; i += 256) {
        const uint2 v = ebuf[i];
        const int d = (int)(v.x >> 16) - b * 128;
        const int pos = atomicAdd(&lh[d], 1);
        sd2[lo + pos] = v.x;
        eid[lo + pos] = (int)v.y;
    }
}

// ---------------------------------------------------------------------------
// h0 = x @ node_W + node_b   [N,128]@[128,64]
// 4 nodes per WAVE, barrier-free; W register-resident (128 VGPR); x inputs
// (2 floats/node) loaded up-front; readlane-broadcast FMAs, 4 indep chains.
// ---------------------------------------------------------------------------
__global__ __launch_bounds__(256, 3) void node_proj_kernel(
    const float* __restrict__ x, const float* __restrict__ W,
    const float* __restrict__ b, float* __restrict__ h, __half* __restrict__ zh)
{
    const int lane = threadIdx.x & 63;
    const int wave = (blockIdx.x * 256 + threadIdx.x) >> 6;   // 0..12499

    float w[IN_DIM];
#pragma unroll
    for (int k = 0; k < IN_DIM; ++k) w[k] = W[k * HID + lane];
    const float bias = b[lane];

    float xa[4], xb[4];
#pragma unroll
    for (int i = 0; i < 4; ++i) {
        const size_t xbase = (size_t)(wave + i * 12500) * IN_DIM;
        xa[i] = x[xbase + lane];
        xb[i] = x[xbase + 64 + lane];
    }

#pragma unroll
    for (int pr = 0; pr < 2; ++pr) {                 // node pairs (0,1),(2,3)
        const int i0 = pr * 2, i1 = pr * 2 + 1;
        float a0 = 0.f, a1 = 0.f, d0 = 0.f, d1 = 0.f;
#pragma unroll
        for (int k = 0; k < 64; ++k) {
            a0 = fmaf(bcast(xa[i0], k), w[k],      a0);
            a1 = fmaf(bcast(xb[i0], k), w[k + 64], a1);
            d0 = fmaf(bcast(xa[i1], k), w[k],      d0);
            d1 = fmaf(bcast(xb[i1], k), w[k + 64], d1);
        }
        const float u0 = (a0 + a1) + bias;
        const float u1 = (d0 + d1) + bias;
        const int n0 = wave + i0 * 12500, n1 = wave + i1 * 12500;
        h[n0 * HID + lane] = u0;
        zh[n0 * HID + lane] = __float2half(u0);
        h[n1 * HID + lane] = u1;
        zh[n1 * HID + lane] = __float2half(u1);
    }
}

// ---------------------------------------------------------------------------
// edge embedding via MFMA (16 edges/wave, K padded 16->32), LDS transpose.
// Grid 3125: 4 tiles per wave -- the grid-stride loop IS the pipeline
// (tile k+1 gathers overlap tile k MFMA/store). One-tile-per-wave measured
// 84us vs 52us here (round 7).
// ---------------------------------------------------------------------------
__global__ __launch_bounds__(256, 4) void edge_emb_kernel(
    const float* __restrict__ ea, const float* __restrict__ W,
    const float* __restrict__ b, const int* __restrict__ eid,
    __half* __restrict__ eah)
{
    __shared__ __half lds_t[4][16 * HID];            // 2KB per wave
    const int lane = threadIdx.x & 63;
    const int waveid = threadIdx.x >> 6;
    const int wave = (blockIdx.x * 256 + threadIdx.x) >> 6;
    const int nwaves = gridDim.x * 4;
    const int m = lane & 15, q = lane >> 4;
    const int NT = N_EDGES / 16;                     // 50000

    half8 bf[4];
#pragma unroll
    for (int blk = 0; blk < 4; ++blk) {
#pragma unroll
        for (int i = 0; i < 8; ++i) {
            const int k = q * 8 + i;
            bf[blk][i] = (k < EDGE_DIM)
                ? (_Float16)W[k * HID + blk * 16 + m] : (_Float16)0.f;
        }
    }
    float bv[4];
#pragma unroll
    for (int blk = 0; blk < 4; ++blk) bv[blk] = b[blk * 16 + m];

    const int ed = lane >> 3, ch = lane & 7;         // store mapping

    for (int tile = wave; tile < NT; tile += nwaves) {
        const int e0 = tile * 16;
        const int eidx = eid[e0 + m];                // gather source row id
        half8 af;
#pragma unroll
        for (int i = 0; i < 8; ++i) af[i] = (_Float16)0.f;
        if (q < 2) {
            const float4* ap =
                (const float4*)(ea + (size_t)eidx * EDGE_DIM + q * 8);
            const float4 lo = ap[0];
            const float4 hi = ap[1];
            af[0] = (_Float16)lo.x; af[1] = (_Float16)lo.y;
            af[2] = (_Float16)lo.z; af[3] = (_Float16)lo.w;
            af[4] = (_Float16)hi.x; af[5] = (_Float16)hi.y;
            af[6] = (_Float16)hi.z; af[7] = (_Float16)hi.w;
        }
        floatx4 c[4];
#pragma unroll
        for (int blk = 0; blk < 4; ++blk) {
            floatx4 cin = {bv[blk], bv[blk], bv[blk], bv[blk]};
            c[blk] = __builtin_amdgcn_mfma_f32_16x16x32_f16(
                af, bf[blk], cin, 0, 0, 0);
        }
#pragma unroll
        for (int blk = 0; blk < 4; ++blk)
#pragma unroll
            for (int r = 0; r < 4; ++r)
                lds_t[waveid][(q * 4 + r) * HID + blk * 16 + m] =
                    __float2half(c[blk][r]);
        // streaming contiguous stores: 2x 16B per lane
        const float4 v0 =
            *(const float4*)&lds_t[waveid][ed * HID + ch * 8];
        const float4 v1 =
            *(const float4*)&lds_t[waveid][(8 + ed) * HID + ch * 8];
        ((float4*)(eah + (size_t)(e0 + ed) * HID))[ch] = v0;
        ((float4*)(eah + (size_t)(e0 + 8 + ed) * HID))[ch] = v1;
    }
}

// ---------------------------------------------------------------------------
// Edge-major segmented softmax-aggregate with interior plain stores
// (round-8 form: one tile per wave, ez[64] issued up-front, no dbuf --
// the round-9 explicit double-buffer spilled to scratch, 85us vs <=51us).
// ---------------------------------------------------------------------------
__global__ __launch_bounds__(256, 3) void edge_agg_kernel(
    const __half* __restrict__ zh, const __half* __restrict__ eah,
    const unsigned* __restrict__ sd2,
    const float* __restrict__ conv_t, int layer,
    float2* __restrict__ ps)
{
    const int lane = threadIdx.x & 63;
    const int wave = (blockIdx.x * 256 + threadIdx.x) >> 6;
    const int nwaves = gridDim.x * 4;
    const float t2 = conv_t[layer] * 1.4426950408889634f;  // log2(e)*t
    const int NT = N_EDGES / 64;                     // 12500

    const _Float16* zf = (const _Float16*)zh;
    const _Float16* ef = (const _Float16*)eah;

    for (int tile = wave; tile < NT; tile += nwaves) {
        const int e0 = tile * 64;
        const unsigned sdv = sd2[e0 + lane];         // one coalesced 4B load
        const _Float16* erow = ef + (size_t)e0 * HID + lane;

        // issue ALL eah streaming loads up-front (no sd2 dependence)
        _Float16 ez[64];
#pragma unroll
        for (int k = 0; k < 64; ++k) ez[k] = erow[(size_t)k * HID];

        const int sv = (int)(sdv & 0xffffu);
        const int dv = (int)(sdv >> 16);
        const int pv = __shfl_up(dv, 1, 64);
        const unsigned long long bmask = __ballot(dv != pv) & ~1ull;

        _Float16 za[16], zb[16];
#pragma unroll
        for (int k = 0; k < 16; ++k) {               // prologue: group 0
            const int a = __builtin_amdgcn_readlane(sv, k);
            za[k] = zf[(size_t)a * HID + lane];
        }

        float S = 0.f, P = 0.f;
        int cur = __builtin_amdgcn_readlane(dv, 0);
        bool first = true;
#pragma unroll
        for (int g = 0; g < 4; ++g) {
            if (g < 3) {                             // prefetch group g+1
#pragma unroll
                for (int k = 0; k < 16; ++k) {
                    const int a = __builtin_amdgcn_readlane(sv, (g + 1) * 16 + k);
                    zb[k] = zf[(size_t)a * HID + lane];
                }
            }
#pragma unroll
            for (int k = 0; k < 16; ++k) {
                const int j = g * 16 + k;
                if (bmask & (1ull << j)) {           // SALU test, uniform
                    float2* addr = &ps[(size_t)cur * HID + lane];
                    if (first) {                     // may span from prev tile
                        unsafeAtomicAdd(&addr->x, P);
                        unsafeAtomicAdd(&addr->y, S);
                        first = false;
                    } else {                         // complete node: store
                        *addr = make_float2(P, S);
                    }
                    S = 0.f; P = 0.f;
                    cur = __builtin_amdgcn_readlane(dv, j);
                }
                _Float16 mh = za[k] + ez[j];
                mh = mh > (_Float16)0.f ? mh : (_Float16)0.f;
                const float mm = (float)mh + 1e-7f;
                const float xx = __builtin_amdgcn_exp2f(mm * t2);
                S += xx;
                P = fmaf(mm, xx, P);
            }
            if (g < 3) {
#pragma unroll
                for (int k = 0; k < 16; ++k) za[k] = zb[k];
            }
        }
        {   // final flush: may span into next tile -> atomic
            float2* addr = &ps[(size_t)cur * HID + lane];
            unsafeAtomicAdd(&addr->x, P);
            unsafeAtomicAdd(&addr->y, S);
        }
    }
}

// ---------------------------------------------------------------------------
// mm1: 4 nodes per WAVE (wave, +12500, +25000, +37500), barrier-free.
// ALL node inputs loaded up-front (loads strictly before the ps re-zero
// stores), then two node-pairs computed back-to-back with 8 independent
// FMA chains and interleaved LN butterflies.
// ---------------------------------------------------------------------------
__global__ __launch_bounds__(256, 3) void node_mm1_kernel(
    float2* __restrict__ ps,
    const __half* __restrict__ zh,
    const float* __restrict__ W1, const float* __restrict__ b1,
    const float* __restrict__ g1, const float* __restrict__ be1,
    __half* __restrict__ vh)
{
    const int lane = threadIdx.x & 63;
    const int wave = (blockIdx.x * 256 + threadIdx.x) >> 6;   // 0..12499

    float wa[HID], wb[HID];
#pragma unroll
    for (int k = 0; k < HID; ++k) {
        wa[k] = W1[k * HID2 + lane];
        wb[k] = W1[k * HID2 + 64 + lane];
    }
    const float ba = b1[lane],  bb = b1[64 + lane];
    const float ga = g1[lane],  gb = g1[64 + lane];
    const float ca = be1[lane], cb = be1[64 + lane];

    int idx[4];
    float2 pv[4];
    float zv[4];
#pragma unroll
    for (int i = 0; i < 4; ++i) idx[i] = (wave + i * 12500) * HID + lane;
#pragma unroll
    for (int i = 0; i < 4; ++i) pv[i] = ps[idx[i]];          // all loads first
#pragma unroll
    for (int i = 0; i < 4; ++i) zv[i] = __half2float(zh[idx[i]]);
#pragma unroll
    for (int i = 0; i < 4; ++i) ps[idx[i]] = make_float2(0.f, 0.f); // re-zero
    float hv[4];
#pragma unroll
    for (int i = 0; i < 4; ++i)
        hv[i] = pv[i].x / (pv[i].y + 1e-16f) + zv[i];

#pragma unroll
    for (int pr = 0; pr < 2; ++pr) {                 // node pairs (0,1),(2,3)
        const float h0 = hv[pr * 2], h1 = hv[pr * 2 + 1];
        float a0 = 0.f, a1 = 0.f, c0 = 0.f, c1 = 0.f;   // node pr*2
        float d0 = 0.f, d1 = 0.f, e0 = 0.f, e1 = 0.f;   // node pr*2+1
#pragma unroll
        for (int k = 0; k < 32; ++k) {
            const float x0 = bcast(h0, k);
            const float x1 = bcast(h0, k + 32);
            const float y0 = bcast(h1, k);
            const float y1 = bcast(h1, k + 32);
            a0 = fmaf(x0, wa[k], a0);
            c0 = fmaf(x0, wb[k], c0);
            a1 = fmaf(x1, wa[k + 32], a1);
            c1 = fmaf(x1, wb[k + 32], c1);
            d0 = fmaf(y0, wa[k], d0);
            e0 = fmaf(y0, wb[k], e0);
            d1 = fmaf(y1, wa[k + 32], d1);
            e1 = fmaf(y1, wb[k + 32], e1);
        }
        const float ua0 = (a0 + a1) + ba, ub0 = (c0 + c1) + bb;
        const float ua1 = (d0 + d1) + ba, ub1 = (e0 + e1) + bb;

        float s0 = ua0 + ub0, s1 = ua1 + ub1;        // LN128, interleaved
#pragma unroll
        for (int o = 1; o < 64; o <<= 1) {
            s0 += __shfl_xor(s0, o, 64);
            s1 += __shfl_xor(s1, o, 64);
        }
        const float mu0 = s0 * (1.f / 128.f), mu1 = s1 * (1.f / 128.f);
        const float da0 = ua0 - mu0, db0 = ub0 - mu0;
        const float da1 = ua1 - mu1, db1 = ub1 - mu1;
        float q0 = fmaf(da0, da0, db0 * db0);
        float q1 = fmaf(da1, da1, db1 * db1);
#pragma unroll
        for (int o = 1; o < 64; o <<= 1) {
            q0 += __shfl_xor(q0, o, 64);
            q1 += __shfl_xor(q1, o, 64);
        }
        const float r0 = rsqrtf(q0 * (1.f / 128.f) + 1e-5f);
        const float r1 = rsqrtf(q1 * (1.f / 128.f) + 1e-5f);
        const float ya0 = da0 * r0 * ga + ca, yb0 = db0 * r0 * gb + cb;
        const float ya1 = da1 * r1 * ga + ca, yb1 = db1 * r1 * gb + cb;
        const size_t v0 = (size_t)(wave + pr * 2 * 12500) * HID2;
        const size_t v1 = (size_t)(wave + (pr * 2 + 1) * 12500) * HID2;
        vh[v0 + lane]      = __float2half(ya0 > 0.f ? ya0 : 0.f);
        vh[v0 + 64 + lane] = __float2half(yb0 > 0.f ? yb0 : 0.f);
        vh[v1 + lane]      = __float2half(ya1 > 0.f ? ya1 : 0.f);
        vh[v1 + 64 + lane] = __float2half(yb1 > 0.f ? yb1 : 0.f);
    }
}

// ---------------------------------------------------------------------------
// mm2: 4 nodes per WAVE (same decomposition as mm1), barrier-free.
// All vh/h inputs loaded up-front; node pairs with 8 indep chains;
// interleaved LN64 butterflies.
// ---------------------------------------------------------------------------
__global__ __launch_bounds__(256, 3) void node_mm2_kernel(
    const __half* __restrict__ vh,
    const float* __restrict__ W2, const float* __restrict__ b2,
    const float* __restrict__ lng, const float* __restrict__ lnb,
    float* __restrict__ h, __half* __restrict__ zh, int residual)
{
    const int lane = threadIdx.x & 63;
    const int wave = (blockIdx.x * 256 + threadIdx.x) >> 6;   // 0..12499

    float wa[HID], wb[HID];     // wa[k]=W2[k][c], wb[k]=W2[k+64][c]
#pragma unroll
    for (int k = 0; k < HID; ++k) {
        wa[k] = W2[k * HID + lane];
        wb[k] = W2[(k + 64) * HID + lane];
    }
    const float bias = b2[lane];
    const float g = lng[lane];
    const float be = lnb[lane];

    int idx[4];
    float f0[4], f1[4], hold[4];
#pragma unroll
    for (int i = 0; i < 4; ++i) idx[i] = (wave + i * 12500) * HID + lane;
#pragma unroll
    for (int i = 0; i < 4; ++i) {
        const size_t vb = (size_t)(wave + i * 12500) * HID2;
        f0[i] = __half2float(vh[vb + lane]);
        f1[i] = __half2float(vh[vb + 64 + lane]);
    }
#pragma unroll
    for (int i = 0; i < 4; ++i) hold[i] = h[idx[i]];

#pragma unroll
    for (int pr = 0; pr < 2; ++pr) {                 // node pairs (0,1),(2,3)
        const int i0 = pr * 2, i1 = pr * 2 + 1;
        float a0 = 0.f, a1 = 0.f, c0 = 0.f, c1 = 0.f;   // node i0
        float d0 = 0.f, d1 = 0.f, e0 = 0.f, e1 = 0.f;   // node i1
#pragma unroll
        for (int k = 0; k < 32; ++k) {
            a0 = fmaf(bcast(f0[i0], k),      wa[k],      a0);
            a1 = fmaf(bcast(f0[i0], k + 32), wa[k + 32], a1);
            c0 = fmaf(bcast(f1[i0], k),      wb[k],      c0);
            c1 = fmaf(bcast(f1[i0], k + 32), wb[k + 32], c1);
            d0 = fmaf(bcast(f0[i1], k),      wa[k],      d0);
            d1 = fmaf(bcast(f0[i1], k + 32), wa[k + 32], d1);
            e0 = fmaf(bcast(f1[i1], k),      wb[k],      e0);
            e1 = fmaf(bcast(f1[i1], k + 32), wb[k + 32], e1);
        }
        const float acc0 = (a0 + a1) + (c0 + c1) + bias;
        const float acc1 = (d0 + d1) + (e0 + e1) + bias;
        const float hn0 = residual ? (hold[i0] + acc0) : acc0;
        const float hn1 = residual ? (hold[i1] + acc1) : acc1;
        h[idx[i0]] = hn0;
        h[idx[i1]] = hn1;

        float s0 = hn0, s1 = hn1;                    // LN64, interleaved
#pragma unroll
        for (int o = 1; o < 64; o <<= 1) {
            s0 += __shfl_xor(s0, o, 64);
            s1 += __shfl_xor(s1, o, 64);
        }
        const float mu0 = s0 * (1.f / 64.f), mu1 = s1 * (1.f / 64.f);
        const float dd0 = hn0 - mu0, dd1 = hn1 - mu1;
        float q0 = dd0 * dd0, q1 = dd1 * dd1;
#pragma unroll
        for (int o = 1; o < 64; o <<= 1) {
            q0 += __shfl_xor(q0, o, 64);
            q1 += __shfl_xor(q1, o, 64);
        }
        const float r0 = rsqrtf(q0 * (1.f / 64.f) + 1e-5f);
        const float r1 = rsqrtf(q1 * (1.f / 64.f) + 1e-5f);
        const float y0 = dd0 * r0 * g + be;
        const float y1 = dd1 * r1 * g + be;
        zh[idx[i0]] = __float2half(y0 > 0.f ? y0 : 0.f);
        zh[idx[i1]] = __float2half(y1 > 0.f ? y1 : 0.f);
    }
}

// ---------------------------------------------------------------------------
// out = zh @ lin_W + lin_b      [N,64]@[64,8]
// ---------------------------------------------------------------------------
__global__ __launch_bounds__(256, 4) void final_kernel(
    const __half* __restrict__ zh, const float* __restrict__ Wl,
    const float* __restrict__ bl, float* __restrict__ out)
{
    __shared__ float wl[HID * OUT_DIM];
    for (int i = threadIdx.x; i < HID * OUT_DIM; i += 256) wl[i] = Wl[i];
    __syncthreads();
    const int total = N_NODES * OUT_DIM;
    for (int idx = blockIdx.x * 256 + threadIdx.x; idx < total;
         idx += gridDim.x * 256) {
        const int n = idx >> 3, o = idx & 7;
        const __half2* zp = (const __half2*)(zh + (size_t)n * HID);
        float acc = bl[o];
#pragma unroll
        for (int k2 = 0; k2 < HID / 2; ++k2) {
            const float2 f = __half22float2(zp[k2]);
            acc = fmaf(f.x, wl[(k2 * 2 + 0) * OUT_DIM + o], acc);
            acc = fmaf(f.y, wl[(k2 * 2 + 1) * OUT_DIM + o], acc);
        }
        out[idx] = acc;
    }
}

// ---------------------------------------------------------------------------
extern "C" void kernel_launch(void* const* d_in, const int* in_sizes, int n_in,
                              void* d_out, int out_size, void* d_ws, size_t ws_size,
                              hipStream_t stream)
{
    const float* x         = (const float*)d_in[0];
    const float* edge_attr = (const float*)d_in[1];
    const float* node_W    = (const float*)d_in[2];
    const float* node_b    = (const float*)d_in[3];
    const float* edge_W    = (const float*)d_in[4];
    const float* edge_b    = (const float*)d_in[5];
    const float* conv_t    = (const float*)d_in[6];
    const float* conv_W1   = (const float*)d_in[7];
    const float* conv_b1   = (const float*)d_in[8];
    const float* conv_g1   = (const float*)d_in[9];
    const float* conv_be1  = (const float*)d_in[10];
    const float* conv_W2   = (const float*)d_in[11];
    const float* conv_b2   = (const float*)d_in[12];
    const float* ln_g      = (const float*)d_in[13];
    const float* ln_b      = (const float*)d_in[14];
    const float* lin_W     = (const float*)d_in[15];
    const float* lin_b     = (const float*)d_in[16];
    const int*   edge_index= (const int*)d_in[17];
    const int*   srcs = edge_index;
    const int*   dsts = edge_index + N_EDGES;
    float* out = (float*)d_out;

    // workspace layout (~173 MB)
    float* h    = (float*)d_ws;                   // N*64
    float2* ps  = (float2*)(h + N_NODES * HID);   // N*64 float2 (P,S packed)
    __half* vh  = (__half*)(ps + N_NODES * HID);  // N*128 half
    __half* zh  = vh + (size_t)N_NODES * HID2;    // N*64 half
    __half* eah = zh + (size_t)N_NODES * HID;     // E*64 half
    uint2* tmp  = (uint2*)(eah + (size_t)N_EDGES * HID); // E x 8B
    unsigned* sd2 = (unsigned*)(tmp + N_EDGES);   // E x 4B
    int* eid    = (int*)(sd2 + N_EDGES);          // E x 4B
    int* ccnt   = eid + N_EDGES;                  // NBUCK
    int* coff   = ccnt + NBUCK;                   // NBUCK+1
    int* ccur   = coff + NBUCK + 1;               // NBUCK

    // ---- two-level counting sort of edges by dst ----
    hipMemsetAsync(ccnt, 0, (size_t)NBUCK * sizeof(int), stream);
    chist_kernel<<<CBLOCKS, 256, 0, stream>>>(dsts, ccnt);
    cscan_kernel<<<1, 256, 0, stream>>>(ccnt, coff, ccur);
    cscatter_kernel<<<CBLOCKS, 256, 0, stream>>>(srcs, dsts, ccur, tmp);
    fsort_kernel<<<NBUCK, 256, 0, stream>>>(tmp, coff, sd2, eid);

    node_proj_kernel<<<3125, 256, 0, stream>>>(x, node_W, node_b, h, zh);
    edge_emb_kernel<<<3125, 256, 0, stream>>>(edge_attr, edge_W, edge_b, eid, eah);

    // zero ps once; node_mm1 re-zeroes it for the next layer
    hipMemsetAsync(ps, 0, (size_t)N_NODES * HID * sizeof(float2), stream);

    for (int layer = 0; layer < N_LAYERS; ++layer) {
        edge_agg_kernel<<<3125, 256, 0, stream>>>(zh, eah, sd2,
                                                  conv_t, layer, ps);
        node_mm1_kernel<<<3125, 256, 0, stream>>>(
            ps, zh,
            conv_W1 + (size_t)layer * HID * HID2, conv_b1 + layer * HID2,
            conv_g1 + layer * HID2, conv_be1 + layer * HID2, vh);
        const float* gz = (layer < N_LAYERS - 1) ? (ln_g + (layer + 1) * HID) : ln_g;
        const float* bz = (layer < N_LAYERS - 1) ? (ln_b + (layer + 1) * HID) : ln_b;
        node_mm2_kernel<<<3125, 256, 0, stream>>>(
            vh, conv_W2 + (size_t)layer * HID2 * HID, conv_b2 + layer * HID,
            gz, bz, h, zh, layer > 0 ? 1 : 0);
    }
    final_kernel<<<1024, 256, 0, stream>>>(zh, lin_W, lin_b, out);
}

// Round 11
// 637.147 us; speedup vs baseline: 1.1582x; 1.0122x over previous
//
#include <hip/hip_runtime.h>
#include <hip/hip_fp16.h>

#define N_NODES 50000
#define N_EDGES 800000
#define IN_DIM  128
#define EDGE_DIM 16
#define HID     64
#define HID2    128
#define OUT_DIM 8
#define N_LAYERS 4
#define NBUCK   391        // ceil(50000/128) buckets of 128 dst nodes
#define CCHUNK  4096       // edges per coarse block
#define CBLOCKS 196        // ceil(800000/4096)

typedef _Float16 half8 __attribute__((ext_vector_type(8)));
typedef float floatx4 __attribute__((ext_vector_type(4)));

// wave-uniform broadcast of lane l's float via v_readlane (SGPR result,
// folds into v_fma as the 1 allowed scalar operand; avoids ds_bpermute)
static __device__ __forceinline__ float bcast(float v, int l) {
    return __uint_as_float(__builtin_amdgcn_readlane(__float_as_uint(v), l));
}

// ---------------------------------------------------------------------------
// Two-level counting sort by dst.
// Entry packing: word0 = src | dst<<16 (both < 2^16), word1 = edge id.
// ---------------------------------------------------------------------------
__global__ __launch_bounds__(256, 4) void chist_kernel(
    const int* __restrict__ dsts, int* __restrict__ ccnt)
{
    __shared__ int lh[NBUCK];
    for (int i = threadIdx.x; i < NBUCK; i += 256) lh[i] = 0;
    __syncthreads();
    const int base = blockIdx.x * CCHUNK;
#pragma unroll
    for (int i = 0; i < 16; ++i) {
        const int e = base + i * 256 + threadIdx.x;
        if (e < N_EDGES) atomicAdd(&lh[dsts[e] >> 7], 1);
    }
    __syncthreads();
    for (int i = threadIdx.x; i < NBUCK; i += 256)
        if (lh[i]) atomicAdd(&ccnt[i], lh[i]);
}

// single block: exclusive scan of 391 bucket counts -> coff[0..391], ccur copy
__global__ __launch_bounds__(256, 1) void cscan_kernel(
    const int* __restrict__ ccnt, int* __restrict__ coff, int* __restrict__ ccur)
{
    __shared__ int part[512];
    const int t = threadIdx.x;
    part[t]       = (t < NBUCK)       ? ccnt[t]       : 0;
    part[t + 256] = (t + 256 < NBUCK) ? ccnt[t + 256] : 0;
    __syncthreads();
    for (int off = 1; off < 512; off <<= 1) {
        const int v0 = (t >= off) ? part[t - off] : 0;
        const int v1 = (t + 256 >= off) ? part[t + 256 - off] : 0;
        __syncthreads();
        part[t] += v0; part[t + 256] += v1;
        __syncthreads();
    }
    if (t < NBUCK) { const int ex = (t > 0) ? part[t - 1] : 0; coff[t] = ex; ccur[t] = ex; }
    const int i2 = t + 256;
    if (i2 < NBUCK) { coff[i2] = part[i2 - 1]; ccur[i2] = part[i2 - 1]; }
    if (t == 0) coff[NBUCK] = part[NBUCK - 1];
}

__global__ __launch_bounds__(256, 4) void cscatter_kernel(
    const int* __restrict__ srcs, const int* __restrict__ dsts,
    int* __restrict__ ccur, uint2* __restrict__ tmp)
{
    __shared__ int lh[NBUCK], lbase[NBUCK], lrank[NBUCK];
    for (int i = threadIdx.x; i < NBUCK; i += 256) { lh[i] = 0; lrank[i] = 0; }
    __syncthreads();
    const int base = blockIdx.x * CCHUNK;
    int myd[16], mys[16];
#pragma unroll
    for (int i = 0; i < 16; ++i) {
        const int e = base + i * 256 + threadIdx.x;
        if (e < N_EDGES) {
            myd[i] = dsts[e]; mys[i] = srcs[e];
            atomicAdd(&lh[myd[i] >> 7], 1);
        } else myd[i] = -1;
    }
    __syncthreads();
    for (int i = threadIdx.x; i < NBUCK; i += 256) {
        const int c = lh[i];
        lbase[i] = c ? atomicAdd(&ccur[i], c) : 0;
    }
    __syncthreads();
#pragma unroll
    for (int i = 0; i < 16; ++i) {
        if (myd[i] >= 0) {
            const int e = base + i * 256 + threadIdx.x;
            const int b = myd[i] >> 7;
            const int r = atomicAdd(&lrank[b], 1);
            tmp[lbase[b] + r] =
                make_uint2((unsigned)mys[i] | ((unsigned)myd[i] << 16),
                           (unsigned)e);
        }
    }
}

// one block per bucket: LDS counting sort over the 128 local dsts
__global__ __launch_bounds__(256, 1) void fsort_kernel(
    const uint2* __restrict__ tmp, const int* __restrict__ coff,
    unsigned* __restrict__ sd2, int* __restrict__ eid)
{
    __shared__ uint2 ebuf[4096];
    __shared__ int lh[128], lsc[128];
    const int b = blockIdx.x;
    const int lo = coff[b];
    const int cnt = coff[b + 1] - lo;
    if (threadIdx.x < 128) lh[threadIdx.x] = 0;
    __syncthreads();
    for (int i = threadIdx.x; i < cnt; i += 256) {
        const uint2 v = tmp[lo + i];
        ebuf[i] = v;
        atomicAdd(&lh[(int)(v.x >> 16) - b * 128], 1);
    }
    __syncthreads();
    if (threadIdx.x < 128) lsc[threadIdx.x] = lh[threadIdx.x];
    __syncthreads();
    for (int off = 1; off < 128; off <<= 1) {
        int v = 0;
        if (threadIdx.x < 128 && threadIdx.x >= off) v = lsc[threadIdx.x - off];
        __syncthreads();
        if (threadIdx.x < 128) lsc[threadIdx.x] += v;
        __syncthreads();
    }
    if (threadIdx.x < 128) lh[threadIdx.x] = lsc[threadIdx.x] - lh[threadIdx.x];
    __syncthreads();
    for (int i = threadIdx.x; i < cnt; i += 256) {
        const uint2 v = ebuf[i];
        const int d = (int)(v.x >> 16) - b * 128;
        const int pos = atomicAdd(&lh[d], 1);
        sd2[lo + pos] = v.x;
        eid[lo + pos] = (int)v.y;
    }
}

// ---------------------------------------------------------------------------
// h0 = x @ node_W + node_b   [N,128]@[128,64]
// 4 nodes per WAVE, barrier-free; W register-resident (128 VGPR); x inputs
// (2 floats/node) loaded up-front; readlane-broadcast FMAs, 4 indep chains.
// ---------------------------------------------------------------------------
__global__ __launch_bounds__(256, 3) void node_proj_kernel(
    const float* __restrict__ x, const float* __restrict__ W,
    const float* __restrict__ b, float* __restrict__ h, __half* __restrict__ zh)
{
    const int lane = threadIdx.x & 63;
    const int wave = (blockIdx.x * 256 + threadIdx.x) >> 6;   // 0..12499

    float w[IN_DIM];
#pragma unroll
    for (int k = 0; k < IN_DIM; ++k) w[k] = W[k * HID + lane];
    const float bias = b[lane];

    float xa[4], xb[4];
#pragma unroll
    for (int i = 0; i < 4; ++i) {
        const size_t xbase = (size_t)(wave + i * 12500) * IN_DIM;
        xa[i] = x[xbase + lane];
        xb[i] = x[xbase + 64 + lane];
    }

#pragma unroll
    for (int pr = 0; pr < 2; ++pr) {                 // node pairs (0,1),(2,3)
        const int i0 = pr * 2, i1 = pr * 2 + 1;
        float a0 = 0.f, a1 = 0.f, d0 = 0.f, d1 = 0.f;
#pragma unroll
        for (int k = 0; k < 64; ++k) {
            a0 = fmaf(bcast(xa[i0], k), w[k],      a0);
            a1 = fmaf(bcast(xb[i0], k), w[k + 64], a1);
            d0 = fmaf(bcast(xa[i1], k), w[k],      d0);
            d1 = fmaf(bcast(xb[i1], k), w[k + 64], d1);
        }
        const float u0 = (a0 + a1) + bias;
        const float u1 = (d0 + d1) + bias;
        const int n0 = wave + i0 * 12500, n1 = wave + i1 * 12500;
        h[n0 * HID + lane] = u0;
        zh[n0 * HID + lane] = __float2half(u0);
        h[n1 * HID + lane] = u1;
        zh[n1 * HID + lane] = __float2half(u1);
    }
}

// ---------------------------------------------------------------------------
// edge embedding via MFMA (16 edges/wave, K padded 16->32), LDS transpose.
// Grid 1563: 8 tiles per wave -- the grid-stride loop IS the pipeline
// (tile k+1 gathers overlap tile k MFMA/store); deeper loop amortizes the
// pipeline fill/drain (1 tile = 84us, 4 tiles = 52us, round 7).
// ---------------------------------------------------------------------------
__global__ __launch_bounds__(256, 4) void edge_emb_kernel(
    const float* __restrict__ ea, const float* __restrict__ W,
    const float* __restrict__ b, const int* __restrict__ eid,
    __half* __restrict__ eah)
{
    __shared__ __half lds_t[4][16 * HID];            // 2KB per wave
    const int lane = threadIdx.x & 63;
    const int waveid = threadIdx.x >> 6;
    const int wave = (blockIdx.x * 256 + threadIdx.x) >> 6;
    const int nwaves = gridDim.x * 4;
    const int m = lane & 15, q = lane >> 4;
    const int NT = N_EDGES / 16;                     // 50000

    half8 bf[4];
#pragma unroll
    for (int blk = 0; blk < 4; ++blk) {
#pragma unroll
        for (int i = 0; i < 8; ++i) {
            const int k = q * 8 + i;
            bf[blk][i] = (k < EDGE_DIM)
                ? (_Float16)W[k * HID + blk * 16 + m] : (_Float16)0.f;
        }
    }
    float bv[4];
#pragma unroll
    for (int blk = 0; blk < 4; ++blk) bv[blk] = b[blk * 16 + m];

    const int ed = lane >> 3, ch = lane & 7;         // store mapping

    for (int tile = wave; tile < NT; tile += nwaves) {
        const int e0 = tile * 16;
        const int eidx = eid[e0 + m];                // gather source row id
        half8 af;
#pragma unroll
        for (int i = 0; i < 8; ++i) af[i] = (_Float16)0.f;
        if (q < 2) {
            const float4* ap =
                (const float4*)(ea + (size_t)eidx * EDGE_DIM + q * 8);
            const float4 lo = ap[0];
            const float4 hi = ap[1];
            af[0] = (_Float16)lo.x; af[1] = (_Float16)lo.y;
            af[2] = (_Float16)lo.z; af[3] = (_Float16)lo.w;
            af[4] = (_Float16)hi.x; af[5] = (_Float16)hi.y;
            af[6] = (_Float16)hi.z; af[7] = (_Float16)hi.w;
        }
        floatx4 c[4];
#pragma unroll
        for (int blk = 0; blk < 4; ++blk) {
            floatx4 cin = {bv[blk], bv[blk], bv[blk], bv[blk]};
            c[blk] = __builtin_amdgcn_mfma_f32_16x16x32_f16(
                af, bf[blk], cin, 0, 0, 0);
        }
#pragma unroll
        for (int blk = 0; blk < 4; ++blk)
#pragma unroll
            for (int r = 0; r < 4; ++r)
                lds_t[waveid][(q * 4 + r) * HID + blk * 16 + m] =
                    __float2half(c[blk][r]);
        // streaming contiguous stores: 2x 16B per lane
        const float4 v0 =
            *(const float4*)&lds_t[waveid][ed * HID + ch * 8];
        const float4 v1 =
            *(const float4*)&lds_t[waveid][(8 + ed) * HID + ch * 8];
        ((float4*)(eah + (size_t)(e0 + ed) * HID))[ch] = v0;
        ((float4*)(eah + (size_t)(e0 + 8 + ed) * HID))[ch] = v1;
    }
}

// ---------------------------------------------------------------------------
// Edge-major segmented softmax-aggregate with interior plain stores
// (round-8 form: one tile per wave, ez[64] issued up-front, no dbuf).
// __launch_bounds__(256,4): 4 blocks/CU (live state ~90 VGPR < 128 cap)
// for +33% latency hiding on the sdv->readlane->za chain.
// ---------------------------------------------------------------------------
__global__ __launch_bounds__(256, 4) void edge_agg_kernel(
    const __half* __restrict__ zh, const __half* __restrict__ eah,
    const unsigned* __restrict__ sd2,
    const float* __restrict__ conv_t, int layer,
    float2* __restrict__ ps)
{
    const int lane = threadIdx.x & 63;
    const int wave = (blockIdx.x * 256 + threadIdx.x) >> 6;
    const int nwaves = gridDim.x * 4;
    const float t2 = conv_t[layer] * 1.4426950408889634f;  // log2(e)*t
    const int NT = N_EDGES / 64;                     // 12500

    const _Float16* zf = (const _Float16*)zh;
    const _Float16* ef = (const _Float16*)eah;

    for (int tile = wave; tile < NT; tile += nwaves) {
        const int e0 = tile * 64;
        const unsigned sdv = sd2[e0 + lane];         // one coalesced 4B load
        const _Float16* erow = ef + (size_t)e0 * HID + lane;

        // issue ALL eah streaming loads up-front (no sd2 dependence)
        _Float16 ez[64];
#pragma unroll
        for (int k = 0; k < 64; ++k) ez[k] = erow[(size_t)k * HID];

        const int sv = (int)(sdv & 0xffffu);
        const int dv = (int)(sdv >> 16);
        const int pv = __shfl_up(dv, 1, 64);
        const unsigned long long bmask = __ballot(dv != pv) & ~1ull;

        _Float16 za[16], zb[16];
#pragma unroll
        for (int k = 0; k < 16; ++k) {               // prologue: group 0
            const int a = __builtin_amdgcn_readlane(sv, k);
            za[k] = zf[(size_t)a * HID + lane];
        }

        float S = 0.f, P = 0.f;
        int cur = __builtin_amdgcn_readlane(dv, 0);
        bool first = true;
#pragma unroll
        for (int g = 0; g < 4; ++g) {
            if (g < 3) {                             // prefetch group g+1
#pragma unroll
                for (int k = 0; k < 16; ++k) {
                    const int a = __builtin_amdgcn_readlane(sv, (g + 1) * 16 + k);
                    zb[k] = zf[(size_t)a * HID + lane];
                }
            }
#pragma unroll
            for (int k = 0; k < 16; ++k) {
                const int j = g * 16 + k;
                if (bmask & (1ull << j)) {           // SALU test, uniform
                    float2* addr = &ps[(size_t)cur * HID + lane];
                    if (first) {                     // may span from prev tile
                        unsafeAtomicAdd(&addr->x, P);
                        unsafeAtomicAdd(&addr->y, S);
                        first = false;
                    } else {                         // complete node: store
                        *addr = make_float2(P, S);
                    }
                    S = 0.f; P = 0.f;
                    cur = __builtin_amdgcn_readlane(dv, j);
                }
                _Float16 mh = za[k] + ez[j];
                mh = mh > (_Float16)0.f ? mh : (_Float16)0.f;
                const float mm = (float)mh + 1e-7f;
                const float xx = __builtin_amdgcn_exp2f(mm * t2);
                S += xx;
                P = fmaf(mm, xx, P);
            }
            if (g < 3) {
#pragma unroll
                for (int k = 0; k < 16; ++k) za[k] = zb[k];
            }
        }
        {   // final flush: may span into next tile -> atomic
            float2* addr = &ps[(size_t)cur * HID + lane];
            unsafeAtomicAdd(&addr->x, P);
            unsafeAtomicAdd(&addr->y, S);
        }
    }
}

// ---------------------------------------------------------------------------
// mm1: 4 nodes per WAVE (wave, +12500, +25000, +37500), barrier-free.
// ALL node inputs loaded up-front (loads strictly before the ps re-zero
// stores), then two node-pairs computed back-to-back with 8 independent
// FMA chains and interleaved LN butterflies.
// ---------------------------------------------------------------------------
__global__ __launch_bounds__(256, 3) void node_mm1_kernel(
    float2* __restrict__ ps,
    const __half* __restrict__ zh,
    const float* __restrict__ W1, const float* __restrict__ b1,
    const float* __restrict__ g1, const float* __restrict__ be1,
    __half* __restrict__ vh)
{
    const int lane = threadIdx.x & 63;
    const int wave = (blockIdx.x * 256 + threadIdx.x) >> 6;   // 0..12499

    float wa[HID], wb[HID];
#pragma unroll
    for (int k = 0; k < HID; ++k) {
        wa[k] = W1[k * HID2 + lane];
        wb[k] = W1[k * HID2 + 64 + lane];
    }
    const float ba = b1[lane],  bb = b1[64 + lane];
    const float ga = g1[lane],  gb = g1[64 + lane];
    const float ca = be1[lane], cb = be1[64 + lane];

    int idx[4];
    float2 pv[4];
    float zv[4];
#pragma unroll
    for (int i = 0; i < 4; ++i) idx[i] = (wave + i * 12500) * HID + lane;
#pragma unroll
    for (int i = 0; i < 4; ++i) pv[i] = ps[idx[i]];          // all loads first
#pragma unroll
    for (int i = 0; i < 4; ++i) zv[i] = __half2float(zh[idx[i]]);
#pragma unroll
    for (int i = 0; i < 4; ++i) ps[idx[i]] = make_float2(0.f, 0.f); // re-zero
    float hv[4];
#pragma unroll
    for (int i = 0; i < 4; ++i)
        hv[i] = pv[i].x / (pv[i].y + 1e-16f) + zv[i];

#pragma unroll
    for (int pr = 0; pr < 2; ++pr) {                 // node pairs (0,1),(2,3)
        const float h0 = hv[pr * 2], h1 = hv[pr * 2 + 1];
        float a0 = 0.f, a1 = 0.f, c0 = 0.f, c1 = 0.f;   // node pr*2
        float d0 = 0.f, d1 = 0.f, e0 = 0.f, e1 = 0.f;   // node pr*2+1
#pragma unroll
        for (int k = 0; k < 32; ++k) {
            const float x0 = bcast(h0, k);
            const float x1 = bcast(h0, k + 32);
            const float y0 = bcast(h1, k);
            const float y1 = bcast(h1, k + 32);
            a0 = fmaf(x0, wa[k], a0);
            c0 = fmaf(x0, wb[k], c0);
            a1 = fmaf(x1, wa[k + 32], a1);
            c1 = fmaf(x1, wb[k + 32], c1);
            d0 = fmaf(y0, wa[k], d0);
            e0 = fmaf(y0, wb[k], e0);
            d1 = fmaf(y1, wa[k + 32], d1);
            e1 = fmaf(y1, wb[k + 32], e1);
        }
        const float ua0 = (a0 + a1) + ba, ub0 = (c0 + c1) + bb;
        const float ua1 = (d0 + d1) + ba, ub1 = (e0 + e1) + bb;

        float s0 = ua0 + ub0, s1 = ua1 + ub1;        // LN128, interleaved
#pragma unroll
        for (int o = 1; o < 64; o <<= 1) {
            s0 += __shfl_xor(s0, o, 64);
            s1 += __shfl_xor(s1, o, 64);
        }
        const float mu0 = s0 * (1.f / 128.f), mu1 = s1 * (1.f / 128.f);
        const float da0 = ua0 - mu0, db0 = ub0 - mu0;
        const float da1 = ua1 - mu1, db1 = ub1 - mu1;
        float q0 = fmaf(da0, da0, db0 * db0);
        float q1 = fmaf(da1, da1, db1 * db1);
#pragma unroll
        for (int o = 1; o < 64; o <<= 1) {
            q0 += __shfl_xor(q0, o, 64);
            q1 += __shfl_xor(q1, o, 64);
        }
        const float r0 = rsqrtf(q0 * (1.f / 128.f) + 1e-5f);
        const float r1 = rsqrtf(q1 * (1.f / 128.f) + 1e-5f);
        const float ya0 = da0 * r0 * ga + ca, yb0 = db0 * r0 * gb + cb;
        const float ya1 = da1 * r1 * ga + ca, yb1 = db1 * r1 * gb + cb;
        const size_t v0 = (size_t)(wave + pr * 2 * 12500) * HID2;
        const size_t v1 = (size_t)(wave + (pr * 2 + 1) * 12500) * HID2;
        vh[v0 + lane]      = __float2half(ya0 > 0.f ? ya0 : 0.f);
        vh[v0 + 64 + lane] = __float2half(yb0 > 0.f ? yb0 : 0.f);
        vh[v1 + lane]      = __float2half(ya1 > 0.f ? ya1 : 0.f);
        vh[v1 + 64 + lane] = __float2half(yb1 > 0.f ? yb1 : 0.f);
    }
}

// ---------------------------------------------------------------------------
// mm2: 4 nodes per WAVE (same decomposition as mm1), barrier-free.
// All vh/h inputs loaded up-front; node pairs with 8 indep chains;
// interleaved LN64 butterflies.
// ---------------------------------------------------------------------------
__global__ __launch_bounds__(256, 3) void node_mm2_kernel(
    const __half* __restrict__ vh,
    const float* __restrict__ W2, const float* __restrict__ b2,
    const float* __restrict__ lng, const float* __restrict__ lnb,
    float* __restrict__ h, __half* __restrict__ zh, int residual)
{
    const int lane = threadIdx.x & 63;
    const int wave = (blockIdx.x * 256 + threadIdx.x) >> 6;   // 0..12499

    float wa[HID], wb[HID];     // wa[k]=W2[k][c], wb[k]=W2[k+64][c]
#pragma unroll
    for (int k = 0; k < HID; ++k) {
        wa[k] = W2[k * HID + lane];
        wb[k] = W2[(k + 64) * HID + lane];
    }
    const float bias = b2[lane];
    const float g = lng[lane];
    const float be = lnb[lane];

    int idx[4];
    float f0[4], f1[4], hold[4];
#pragma unroll
    for (int i = 0; i < 4; ++i) idx[i] = (wave + i * 12500) * HID + lane;
#pragma unroll
    for (int i = 0; i < 4; ++i) {
        const size_t vb = (size_t)(wave + i * 12500) * HID2;
        f0[i] = __half2float(vh[vb + lane]);
        f1[i] = __half2float(vh[vb + 64 + lane]);
    }
#pragma unroll
    for (int i = 0; i < 4; ++i) hold[i] = h[idx[i]];

#pragma unroll
    for (int pr = 0; pr < 2; ++pr) {                 // node pairs (0,1),(2,3)
        const int i0 = pr * 2, i1 = pr * 2 + 1;
        float a0 = 0.f, a1 = 0.f, c0 = 0.f, c1 = 0.f;   // node i0
        float d0 = 0.f, d1 = 0.f, e0 = 0.f, e1 = 0.f;   // node i1
#pragma unroll
        for (int k = 0; k < 32; ++k) {
            a0 = fmaf(bcast(f0[i0], k),      wa[k],      a0);
            a1 = fmaf(bcast(f0[i0], k + 32), wa[k + 32], a1);
            c0 = fmaf(bcast(f1[i0], k),      wb[k],      c0);
            c1 = fmaf(bcast(f1[i0], k + 32), wb[k + 32], c1);
            d0 = fmaf(bcast(f0[i1], k),      wa[k],      d0);
            d1 = fmaf(bcast(f0[i1], k + 32), wa[k + 32], d1);
            e0 = fmaf(bcast(f1[i1], k),      wb[k],      e0);
            e1 = fmaf(bcast(f1[i1], k + 32), wb[k + 32], e1);
        }
        const float acc0 = (a0 + a1) + (c0 + c1) + bias;
        const float acc1 = (d0 + d1) + (e0 + e1) + bias;
        const float hn0 = residual ? (hold[i0] + acc0) : acc0;
        const float hn1 = residual ? (hold[i1] + acc1) : acc1;
        h[idx[i0]] = hn0;
        h[idx[i1]] = hn1;

        float s0 = hn0, s1 = hn1;                    // LN64, interleaved
#pragma unroll
        for (int o = 1; o < 64; o <<= 1) {
            s0 += __shfl_xor(s0, o, 64);
            s1 += __shfl_xor(s1, o, 64);
        }
        const float mu0 = s0 * (1.f / 64.f), mu1 = s1 * (1.f / 64.f);
        const float dd0 = hn0 - mu0, dd1 = hn1 - mu1;
        float q0 = dd0 * dd0, q1 = dd1 * dd1;
#pragma unroll
        for (int o = 1; o < 64; o <<= 1) {
            q0 += __shfl_xor(q0, o, 64);
            q1 += __shfl_xor(q1, o, 64);
        }
        const float r0 = rsqrtf(q0 * (1.f / 64.f) + 1e-5f);
        const float r1 = rsqrtf(q1 * (1.f / 64.f) + 1e-5f);
        const float y0 = dd0 * r0 * g + be;
        const float y1 = dd1 * r1 * g + be;
        zh[idx[i0]] = __float2half(y0 > 0.f ? y0 : 0.f);
        zh[idx[i1]] = __float2half(y1 > 0.f ? y1 : 0.f);
    }
}

// ---------------------------------------------------------------------------
// out = zh @ lin_W + lin_b      [N,64]@[64,8]
// ---------------------------------------------------------------------------
__global__ __launch_bounds__(256, 4) void final_kernel(
    const __half* __restrict__ zh, const float* __restrict__ Wl,
    const float* __restrict__ bl, float* __restrict__ out)
{
    __shared__ float wl[HID * OUT_DIM];
    for (int i = threadIdx.x; i < HID * OUT_DIM; i += 256) wl[i] = Wl[i];
    __syncthreads();
    const int total = N_NODES * OUT_DIM;
    for (int idx = blockIdx.x * 256 + threadIdx.x; idx < total;
         idx += gridDim.x * 256) {
        const int n = idx >> 3, o = idx & 7;
        const __half2* zp = (const __half2*)(zh + (size_t)n * HID);
        float acc = bl[o];
#pragma unroll
        for (int k2 = 0; k2 < HID / 2; ++k2) {
            const float2 f = __half22float2(zp[k2]);
            acc = fmaf(f.x, wl[(k2 * 2 + 0) * OUT_DIM + o], acc);
            acc = fmaf(f.y, wl[(k2 * 2 + 1) * OUT_DIM + o], acc);
        }
        out[idx] = acc;
    }
}

// ---------------------------------------------------------------------------
extern "C" void kernel_launch(void* const* d_in, const int* in_sizes, int n_in,
                              void* d_out, int out_size, void* d_ws, size_t ws_size,
                              hipStream_t stream)
{
    const float* x         = (const float*)d_in[0];
    const float* edge_attr = (const float*)d_in[1];
    const float* node_W    = (const float*)d_in[2];
    const float* node_b    = (const float*)d_in[3];
    const float* edge_W    = (const float*)d_in[4];
    const float* edge_b    = (const float*)d_in[5];
    const float* conv_t    = (const float*)d_in[6];
    const float* conv_W1   = (const float*)d_in[7];
    const float* conv_b1   = (const float*)d_in[8];
    const float* conv_g1   = (const float*)d_in[9];
    const float* conv_be1  = (const float*)d_in[10];
    const float* conv_W2   = (const float*)d_in[11];
    const float* conv_b2   = (const float*)d_in[12];
    const float* ln_g      = (const float*)d_in[13];
    const float* ln_b      = (const float*)d_in[14];
    const float* lin_W     = (const float*)d_in[15];
    const float* lin_b     = (const float*)d_in[16];
    const int*   edge_index= (const int*)d_in[17];
    const int*   srcs = edge_index;
    const int*   dsts = edge_index + N_EDGES;
    float* out = (float*)d_out;

    // workspace layout (~173 MB)
    float* h    = (float*)d_ws;                   // N*64
    float2* ps  = (float2*)(h + N_NODES * HID);   // N*64 float2 (P,S packed)
    __half* vh  = (__half*)(ps + N_NODES * HID);  // N*128 half
    __half* zh  = vh + (size_t)N_NODES * HID2;    // N*64 half
    __half* eah = zh + (size_t)N_NODES * HID;     // E*64 half
    uint2* tmp  = (uint2*)(eah + (size_t)N_EDGES * HID); // E x 8B
    unsigned* sd2 = (unsigned*)(tmp + N_EDGES);   // E x 4B
    int* eid    = (int*)(sd2 + N_EDGES);          // E x 4B
    int* ccnt   = eid + N_EDGES;                  // NBUCK
    int* coff   = ccnt + NBUCK;                   // NBUCK+1
    int* ccur   = coff + NBUCK + 1;               // NBUCK

    // ---- two-level counting sort of edges by dst ----
    hipMemsetAsync(ccnt, 0, (size_t)NBUCK * sizeof(int), stream);
    chist_kernel<<<CBLOCKS, 256, 0, stream>>>(dsts, ccnt);
    cscan_kernel<<<1, 256, 0, stream>>>(ccnt, coff, ccur);
    cscatter_kernel<<<CBLOCKS, 256, 0, stream>>>(srcs, dsts, ccur, tmp);
    fsort_kernel<<<NBUCK, 256, 0, stream>>>(tmp, coff, sd2, eid);

    node_proj_kernel<<<3125, 256, 0, stream>>>(x, node_W, node_b, h, zh);
    edge_emb_kernel<<<1563, 256, 0, stream>>>(edge_attr, edge_W, edge_b, eid, eah);

    // zero ps once; node_mm1 re-zeroes it for the next layer
    hipMemsetAsync(ps, 0, (size_t)N_NODES * HID * sizeof(float2), stream);

    for (int layer = 0; layer < N_LAYERS; ++layer) {
        edge_agg_kernel<<<3125, 256, 0, stream>>>(zh, eah, sd2,
                                                  conv_t, layer, ps);
        node_mm1_kernel<<<3125, 256, 0, stream>>>(
            ps, zh,
            conv_W1 + (size_t)layer * HID * HID2, conv_b1 + layer * HID2,
            conv_g1 + layer * HID2, conv_be1 + layer * HID2, vh);
        const float* gz = (layer < N_LAYERS - 1) ? (ln_g + (layer + 1) * HID) : ln_g;
        const float* bz = (layer < N_LAYERS - 1) ? (ln_b + (layer + 1) * HID) : ln_b;
        node_mm2_kernel<<<3125, 256, 0, stream>>>(
            vh, conv_W2 + (size_t)layer * HID2 * HID, conv_b2 + layer * HID,
            gz, bz, h, zh, layer > 0 ? 1 : 0);
    }
    final_kernel<<<1024, 256, 0, stream>>>(zh, lin_W, lin_b, out);
}